// Round 3
// baseline (525.342 us; speedup 1.0000x reference)
//
#include <hip/hip_runtime.h>
#include <hip/hip_bf16.h>

#define N_NODES 65536
#define IN_CH 512
#define HIDDEN 256
#define OUT_CH 8
#define NUM_GRAPHS 32
#define MAX_LEN 4096
#define BN_EPS 1e-5f
#define BN_BLOCKS 2048

using short8  = __attribute__((ext_vector_type(8))) short;
using floatx4 = __attribute__((ext_vector_type(4))) float;
typedef unsigned int u32;
typedef unsigned short u16;

__device__ inline u16 f2b(float f) {
    u32 u = __float_as_uint(f);
    u += 0x7FFFu + ((u >> 16) & 1u);
    return (u16)(u >> 16);
}
__device__ inline float b2f(u16 h) { return __uint_as_float(((u32)h) << 16); }
__device__ inline float gelu_f(float x) {
    return 0.5f * x * (1.0f + erff(x * 0.70710678118654752f));
}
__device__ inline void load_lds16(const void* g, void* l) {
    __builtin_amdgcn_global_load_lds(
        (const __attribute__((address_space(1))) u32*)g,
        (__attribute__((address_space(3))) u32*)l, 16, 0, 0);
}
// XOR swizzle of 16B groups within a 128B span: kills LDS bank conflicts for
// row-stride power-of-2 tiles. Self-inverse.
__device__ inline int swz(int row, int g) { return (g & ~7) | ((g ^ row) & 7); }

// ---- fused: per-channel sum/sumsq partials + raw bf16 cast of x ----
__global__ __launch_bounds__(256) void statscast_k(const float* __restrict__ x,
                                                   u16* __restrict__ xb,
                                                   float4* __restrict__ partials) {
    __shared__ float4 sS[128];
    __shared__ float4 sQ[128];
    int tid = threadIdx.x;
    int half = tid >> 7;
    int c = tid & 127;                  // float4 column (512ch = 128 float4)
    const float4* x4 = (const float4*)x;
    uint2* xb2 = (uint2*)xb;
    float4 s = make_float4(0.f, 0.f, 0.f, 0.f);
    float4 q = make_float4(0.f, 0.f, 0.f, 0.f);
    int row0 = blockIdx.x * 32;
#pragma unroll
    for (int r = half; r < 32; r += 2) {
        size_t off = (size_t)(row0 + r) * 128 + c;
        float4 v = x4[off];
        s.x += v.x; s.y += v.y; s.z += v.z; s.w += v.w;
        q.x += v.x * v.x; q.y += v.y * v.y; q.z += v.z * v.z; q.w += v.w * v.w;
        uint2 o;
        o.x = (u32)f2b(v.x) | ((u32)f2b(v.y) << 16);
        o.y = (u32)f2b(v.z) | ((u32)f2b(v.w) << 16);
        xb2[off] = o;
    }
    if (half == 1) { sS[c] = s; sQ[c] = q; }
    __syncthreads();
    if (half == 0) {
        float4 s2 = sS[c], q2 = sQ[c];
        s.x += s2.x; s.y += s2.y; s.z += s2.z; s.w += s2.w;
        q.x += q2.x; q.y += q2.y; q.z += q2.z; q.w += q2.w;
        partials[(size_t)blockIdx.x * 256 + c * 2]     = make_float4(s.x, q.x, s.y, q.y);
        partials[(size_t)blockIdx.x * 256 + c * 2 + 1] = make_float4(s.z, q.z, s.w, q.w);
    }
}

// ---- reduce partials -> scale/shift (block g handles channels 2g, 2g+1) ----
__global__ __launch_bounds__(256) void bn_reduce_k(const float4* __restrict__ partials,
                                                   const float* __restrict__ gamma,
                                                   const float* __restrict__ beta,
                                                   float* __restrict__ scale,
                                                   float* __restrict__ shift) {
    __shared__ float4 sd[256];
    int tid = threadIdx.x;
    int g = blockIdx.x;
    float4 a = make_float4(0.f, 0.f, 0.f, 0.f);
    for (int r = tid; r < BN_BLOCKS; r += 256) {
        float4 v = partials[(size_t)r * 256 + g];
        a.x += v.x; a.y += v.y; a.z += v.z; a.w += v.w;
    }
    sd[tid] = a;
    __syncthreads();
    for (int st = 128; st > 0; st >>= 1) {
        if (tid < st) {
            float4 b = sd[tid + st];
            float4 m = sd[tid];
            m.x += b.x; m.y += b.y; m.z += b.z; m.w += b.w;
            sd[tid] = m;
        }
        __syncthreads();
    }
    if (tid == 0) {
        float4 t = sd[0];
        int c0 = g * 2, c1 = g * 2 + 1;
        const float inv = 1.0f / N_NODES;
        float mu0 = t.x * inv, var0 = t.y * inv - mu0 * mu0;
        float mu1 = t.z * inv, var1 = t.w * inv - mu1 * mu1;
        float sc0 = gamma[c0] * rsqrtf(var0 + BN_EPS);
        float sc1 = gamma[c1] * rsqrtf(var1 + BN_EPS);
        scale[c0] = sc0; shift[c0] = beta[c0] - mu0 * sc0;
        scale[c1] = sc1; shift[c1] = beta[c1] - mu1 * sc1;
    }
}

// ---- weight prep: W1T = bf16(scale[k]*W1[k,m]) [M,K]; W2T/W3T plain; offsets ----
__global__ __launch_bounds__(256) void wprep_k(const float* __restrict__ W1,
                                               const float* __restrict__ W2,
                                               const float* __restrict__ W3,
                                               const float* __restrict__ scale,
                                               u16* __restrict__ W1T,
                                               u16* __restrict__ W2T,
                                               u16* __restrict__ W3T,
                                               const int* __restrict__ batch,
                                               int* __restrict__ offsets) {
    int idx = blockIdx.x * 256 + threadIdx.x;
    if (idx < 262144) {                       // W1 [512,512]
        int k = idx >> 9, m = idx & 511;
        W1T[(size_t)m * 512 + k] = f2b(scale[k] * W1[idx]);
    } else if (idx < 262144 + 131072) {       // W2 [512,256]
        int i = idx - 262144;
        int k = i >> 8, m = i & 255;
        W2T[(size_t)m * 512 + k] = f2b(W2[i]);
    } else {                                  // W3 [256,256]
        int i = idx - 393216;
        int k = i >> 8, m = i & 255;
        W3T[(size_t)m * 256 + k] = f2b(W3[i]);
    }
    if (blockIdx.x == 0 && threadIdx.x < NUM_GRAPHS) {
        int gph = threadIdx.x;
        int lo = 0, hi = N_NODES;
        while (lo < hi) {
            int mid = (lo + hi) >> 1;
            if (batch[mid] < gph) lo = mid + 1; else hi = mid;
        }
        offsets[gph] = lo;
    }
}

// ---- folded bias: b1f[m] = b1[m] + sum_k shift[k]*W1[k,m] ----
__global__ __launch_bounds__(128) void b1fold_k(const float* __restrict__ W1,
                                                const float* __restrict__ b1,
                                                const float* __restrict__ shift,
                                                float* __restrict__ b1f) {
    int m = blockIdx.x * 128 + threadIdx.x;   // 4 blocks x 128 = 512
    float acc = b1[m];
#pragma unroll 16
    for (int k = 0; k < 512; ++k) acc += shift[k] * W1[k * 512 + m];
    b1f[m] = acc;
}

// fill entire output with head(bo) (value at padded positions)
__global__ __launch_bounds__(256) void fill_k(float* __restrict__ out,
                                              const float* __restrict__ bo,
                                              const float* __restrict__ alpha_p,
                                              const float* __restrict__ dyt_w,
                                              const float* __restrict__ dyt_b) {
    int idx = blockIdx.x * 256 + threadIdx.x;   // float4 index, 262144 total
    float alpha = alpha_p[0];
    int c0 = (idx * 4) & 7;
    float4 v;
    float* pv = &v.x;
#pragma unroll
    for (int e = 0; e < 4; ++e) {
        int c = c0 + e;
        float a = gelu_f(bo[c]);
        a = dyt_w[c] * tanhf(alpha * a) + dyt_b[c];
        pv[e] = tanhf(a);
    }
    ((float4*)out)[idx] = v;
}

// =================== fused MLP + head ===================
// Block: 32 rows, 256 threads (4 waves). A stays in LDS; weights stream
// global->VGPR (L2-hot); h1/h2/h3 live only in LDS; head fused. No barriers
// inside K-loops; 5 barriers total per block.
__global__ __launch_bounds__(256, 2) void fused_mlp_k(
    const u16* __restrict__ xb, const u16* __restrict__ W1T,
    const u16* __restrict__ W2T, const u16* __restrict__ W3T,
    const float* __restrict__ b1f, const float* __restrict__ b2,
    const float* __restrict__ b3, const float* __restrict__ Wo,
    const float* __restrict__ bo, const int* __restrict__ batch,
    const int* __restrict__ offsets, const float* __restrict__ alpha_p,
    const float* __restrict__ dyt_w, const float* __restrict__ dyt_b,
    float* __restrict__ out)
{
    __shared__ __align__(16) u16 R0[32 * 512];   // 32KB: A, later h2 (16KB) / Wo f32 (8KB)
    __shared__ __align__(16) u16 R1[32 * 512];   // 32KB: h1, later h3 (16KB)
    int tid = threadIdx.x;
    int lane = tid & 63;
    int w = tid >> 6;
    int l15 = lane & 15;
    int q = lane >> 4;
    int row0 = blockIdx.x * 32;

    // ---- phase 0: stage A (32x512 bf16) into R0, swizzled ----
#pragma unroll
    for (int s = 0; s < 8; ++s) {
        int li = s * 256 + tid;
        int r = li >> 6;
        int g = li & 63;
        int gl = swz(r, g);
        load_lds16(&xb[(size_t)(row0 + r) * 512 + gl * 8], &R0[li * 8]);
    }
    __syncthreads();

    // ---- g1: h1[32x512] = gelu(A @ W1T^T + b1f), wave w covers cols [w*128, w*128+128) ----
    {
        floatx4 acc[2][8] = {};
        const u16* bbase = W1T + (size_t)(w * 128 + l15) * 512 + q * 8;
#pragma unroll
        for (int kc = 0; kc < 16; ++kc) {
            short8 bg[8], af[2];
#pragma unroll
            for (int ct = 0; ct < 8; ++ct)
                bg[ct] = *(const short8*)(bbase + (size_t)ct * 16 * 512 + kc * 32);
#pragma unroll
            for (int rt = 0; rt < 2; ++rt) {
                int row = rt * 16 + l15;
                int gp = swz(row, kc * 4 + q);
                af[rt] = *(const short8*)&R0[row * 512 + gp * 8];
            }
#pragma unroll
            for (int rt = 0; rt < 2; ++rt)
#pragma unroll
                for (int ct = 0; ct < 8; ++ct)
                    acc[rt][ct] = __builtin_amdgcn_mfma_f32_16x16x32_bf16(af[rt], bg[ct], acc[rt][ct], 0, 0, 0);
        }
#pragma unroll
        for (int ct = 0; ct < 8; ++ct) {
            int cglob = w * 128 + ct * 16 + l15;
            float bias = b1f[cglob];
            int g = cglob >> 3, c7 = cglob & 7;
#pragma unroll
            for (int rt = 0; rt < 2; ++rt)
#pragma unroll
                for (int reg = 0; reg < 4; ++reg) {
                    int row = rt * 16 + q * 4 + reg;
                    float v = gelu_f(acc[rt][ct][reg] + bias);
                    R1[row * 512 + swz(row, g) * 8 + c7] = f2b(v);
                }
        }
    }
    __syncthreads();

    // ---- g2: h2[32x256] = gelu(h1 @ W2T^T + b2), wave w covers cols [w*64, w*64+64) ----
    {
        floatx4 acc[2][4] = {};
        const u16* bbase = W2T + (size_t)(w * 64 + l15) * 512 + q * 8;
#pragma unroll
        for (int kc = 0; kc < 16; ++kc) {
            short8 bg[4], af[2];
#pragma unroll
            for (int ct = 0; ct < 4; ++ct)
                bg[ct] = *(const short8*)(bbase + (size_t)ct * 16 * 512 + kc * 32);
#pragma unroll
            for (int rt = 0; rt < 2; ++rt) {
                int row = rt * 16 + l15;
                int gp = swz(row, kc * 4 + q);
                af[rt] = *(const short8*)&R1[row * 512 + gp * 8];
            }
#pragma unroll
            for (int rt = 0; rt < 2; ++rt)
#pragma unroll
                for (int ct = 0; ct < 4; ++ct)
                    acc[rt][ct] = __builtin_amdgcn_mfma_f32_16x16x32_bf16(af[rt], bg[ct], acc[rt][ct], 0, 0, 0);
        }
#pragma unroll
        for (int ct = 0; ct < 4; ++ct) {
            int cglob = w * 64 + ct * 16 + l15;
            float bias = b2[cglob];
            int g = cglob >> 3, c7 = cglob & 7;
#pragma unroll
            for (int rt = 0; rt < 2; ++rt)
#pragma unroll
                for (int reg = 0; reg < 4; ++reg) {
                    int row = rt * 16 + q * 4 + reg;
                    float v = gelu_f(acc[rt][ct][reg] + bias);
                    R0[row * 256 + swz(row, g) * 8 + c7] = f2b(v);
                }
        }
    }
    __syncthreads();

    // ---- g3: h3[32x256] = h2 @ W3T^T + b3 (no act) ----
    {
        floatx4 acc[2][4] = {};
        const u16* bbase = W3T + (size_t)(w * 64 + l15) * 256 + q * 8;
#pragma unroll
        for (int kc = 0; kc < 8; ++kc) {
            short8 bg[4], af[2];
#pragma unroll
            for (int ct = 0; ct < 4; ++ct)
                bg[ct] = *(const short8*)(bbase + (size_t)ct * 16 * 256 + kc * 32);
#pragma unroll
            for (int rt = 0; rt < 2; ++rt) {
                int row = rt * 16 + l15;
                int gp = swz(row, kc * 4 + q);
                af[rt] = *(const short8*)&R0[row * 256 + gp * 8];
            }
#pragma unroll
            for (int rt = 0; rt < 2; ++rt)
#pragma unroll
                for (int ct = 0; ct < 4; ++ct)
                    acc[rt][ct] = __builtin_amdgcn_mfma_f32_16x16x32_bf16(af[rt], bg[ct], acc[rt][ct], 0, 0, 0);
        }
#pragma unroll
        for (int ct = 0; ct < 4; ++ct) {
            int cglob = w * 64 + ct * 16 + l15;
            float bias = b3[cglob];
            int g = cglob >> 3, c7 = cglob & 7;
#pragma unroll
            for (int rt = 0; rt < 2; ++rt)
#pragma unroll
                for (int reg = 0; reg < 4; ++reg) {
                    int row = rt * 16 + q * 4 + reg;
                    float v = acc[rt][ct][reg] + bias;
                    R1[row * 256 + swz(row, g) * 8 + c7] = f2b(v);
                }
        }
    }
    __syncthreads();

    // ---- head: out = tanh(dyt_w*tanh(alpha*gelu(h3 @ Wo + bo)) + dyt_b) ----
    float* sWo = (float*)R0;    // h2 dead; 2048 floats = 8KB
#pragma unroll
    for (int i = 0; i < 8; ++i) sWo[i * 256 + tid] = Wo[i * 256 + tid];
    __syncthreads();

    int hrow = tid >> 3;        // 32 rows, 8 threads each
    int hq = tid & 7;
    float a8[8] = {0.f, 0.f, 0.f, 0.f, 0.f, 0.f, 0.f, 0.f};
#pragma unroll
    for (int gi = 0; gi < 4; ++gi) {
        int g = hq * 4 + gi;
        int gp = swz(hrow, g);
        short8 hv = *(const short8*)&R1[hrow * 256 + gp * 8];
#pragma unroll
        for (int e = 0; e < 8; ++e) {
            float h = b2f((u16)hv[e]);
            const float* wr = &sWo[(hq * 32 + gi * 8 + e) * 8];
#pragma unroll
            for (int c = 0; c < 8; ++c) a8[c] += h * wr[c];
        }
    }
#pragma unroll
    for (int st = 1; st < 8; st <<= 1)
#pragma unroll
        for (int c = 0; c < 8; ++c) a8[c] += __shfl_xor(a8[c], st);
    if (hq == 0) {
        int n = row0 + hrow;
        int gph = batch[n];
        int p = n - offsets[gph];
        float alpha = alpha_p[0];
        float r8[8];
#pragma unroll
        for (int c = 0; c < 8; ++c) {
            float a = gelu_f(a8[c] + bo[c]);
            a = dyt_w[c] * tanhf(alpha * a) + dyt_b[c];
            r8[c] = tanhf(a);
        }
        float4* o = (float4*)(out + ((size_t)p * NUM_GRAPHS + gph) * OUT_CH);
        o[0] = make_float4(r8[0], r8[1], r8[2], r8[3]);
        o[1] = make_float4(r8[4], r8[5], r8[6], r8[7]);
    }
}

extern "C" void kernel_launch(void* const* d_in, const int* in_sizes, int n_in,
                              void* d_out, int out_size, void* d_ws, size_t ws_size,
                              hipStream_t stream) {
    (void)in_sizes; (void)n_in; (void)out_size; (void)ws_size;
    const float* x_res = (const float*)d_in[0];
    const int*   batch = (const int*)d_in[1];
    const float* gamma = (const float*)d_in[2];
    const float* beta  = (const float*)d_in[3];
    const float* W1    = (const float*)d_in[4];
    const float* b1    = (const float*)d_in[5];
    const float* W2    = (const float*)d_in[6];
    const float* b2    = (const float*)d_in[7];
    const float* W3    = (const float*)d_in[8];
    const float* b3    = (const float*)d_in[9];
    const float* Wo    = (const float*)d_in[10];
    const float* bo    = (const float*)d_in[11];
    const float* alpha = (const float*)d_in[12];
    const float* dyt_w = (const float*)d_in[13];
    const float* dyt_b = (const float*)d_in[14];
    float* out = (float*)d_out;

    char* ws = (char*)d_ws;
    float* scale = (float*)(ws + 0);
    float* shift = (float*)(ws + 2048);
    float* b1f   = (float*)(ws + 4096);
    int*   offs  = (int*)(ws + 8192);
    u16* W1T = (u16*)(ws + 16384);                       // 512KB
    u16* W2T = (u16*)(ws + 16384 + 524288);              // 256KB
    u16* W3T = (u16*)(ws + 16384 + 524288 + 262144);     // 128KB
    const size_t MB = 1024 * 1024;
    u16* xb = (u16*)(ws + 2 * MB);              // 64MB  [2,66)
    float4* partials = (float4*)(ws + 66 * MB); // 8MB

    fill_k<<<1024, 256, 0, stream>>>(out, bo, alpha, dyt_w, dyt_b);
    statscast_k<<<BN_BLOCKS, 256, 0, stream>>>(x_res, xb, partials);
    bn_reduce_k<<<256, 256, 0, stream>>>(partials, gamma, beta, scale, shift);
    wprep_k<<<1792, 256, 0, stream>>>(W1, W2, W3, scale, W1T, W2T, W3T, batch, offs);
    b1fold_k<<<4, 128, 0, stream>>>(W1, b1, shift, b1f);
    fused_mlp_k<<<2048, 256, 0, stream>>>(xb, W1T, W2T, W3T, b1f, b2, b3, Wo, bo,
                                          batch, offs, alpha, dyt_w, dyt_b, out);
}

// Round 4
// 446.799 us; speedup vs baseline: 1.1758x; 1.1758x over previous
//
#include <hip/hip_runtime.h>
#include <hip/hip_bf16.h>

#define N_NODES 65536
#define IN_CH 512
#define HIDDEN 256
#define OUT_CH 8
#define NUM_GRAPHS 32
#define MAX_LEN 4096
#define BN_EPS 1e-5f
#define BN_BLOCKS 2048

using short8  = __attribute__((ext_vector_type(8))) short;
using floatx4 = __attribute__((ext_vector_type(4))) float;
typedef unsigned int u32;
typedef unsigned short u16;

__device__ inline u16 f2b(float f) {
    u32 u = __float_as_uint(f);
    u += 0x7FFFu + ((u >> 16) & 1u);
    return (u16)(u >> 16);
}
__device__ inline float gelu_f(float x) {
    return 0.5f * x * (1.0f + erff(x * 0.70710678118654752f));
}
__device__ inline void load_lds16(const void* g, void* l) {
    __builtin_amdgcn_global_load_lds(
        (const __attribute__((address_space(1))) u32*)g,
        (__attribute__((address_space(3))) u32*)l, 16, 0, 0);
}

// ---- fused: per-channel sum/sumsq partials + raw bf16 cast of x ----
__global__ __launch_bounds__(256) void statscast_k(const float* __restrict__ x,
                                                   u16* __restrict__ xb,
                                                   float4* __restrict__ partials) {
    __shared__ float4 sS[128];
    __shared__ float4 sQ[128];
    int tid = threadIdx.x;
    int half = tid >> 7;
    int c = tid & 127;                  // float4 column (512ch = 128 float4)
    const float4* x4 = (const float4*)x;
    uint2* xb2 = (uint2*)xb;
    float4 s = make_float4(0.f, 0.f, 0.f, 0.f);
    float4 q = make_float4(0.f, 0.f, 0.f, 0.f);
    int row0 = blockIdx.x * 32;
#pragma unroll
    for (int r = half; r < 32; r += 2) {
        size_t off = (size_t)(row0 + r) * 128 + c;
        float4 v = x4[off];
        s.x += v.x; s.y += v.y; s.z += v.z; s.w += v.w;
        q.x += v.x * v.x; q.y += v.y * v.y; q.z += v.z * v.z; q.w += v.w * v.w;
        uint2 o;
        o.x = (u32)f2b(v.x) | ((u32)f2b(v.y) << 16);
        o.y = (u32)f2b(v.z) | ((u32)f2b(v.w) << 16);
        xb2[off] = o;
    }
    if (half == 1) { sS[c] = s; sQ[c] = q; }
    __syncthreads();
    if (half == 0) {
        float4 s2 = sS[c], q2 = sQ[c];
        s.x += s2.x; s.y += s2.y; s.z += s2.z; s.w += s2.w;
        q.x += q2.x; q.y += q2.y; q.z += q2.z; q.w += q2.w;
        partials[(size_t)blockIdx.x * 256 + c * 2]     = make_float4(s.x, q.x, s.y, q.y);
        partials[(size_t)blockIdx.x * 256 + c * 2 + 1] = make_float4(s.z, q.z, s.w, q.w);
    }
}

// ---- reduce partials -> scale/shift (block g handles channels 2g, 2g+1) ----
__global__ __launch_bounds__(256) void bn_reduce_k(const float4* __restrict__ partials,
                                                   const float* __restrict__ gamma,
                                                   const float* __restrict__ beta,
                                                   float* __restrict__ scale,
                                                   float* __restrict__ shift) {
    __shared__ float4 sd[256];
    int tid = threadIdx.x;
    int g = blockIdx.x;
    float4 a = make_float4(0.f, 0.f, 0.f, 0.f);
    for (int r = tid; r < BN_BLOCKS; r += 256) {
        float4 v = partials[(size_t)r * 256 + g];
        a.x += v.x; a.y += v.y; a.z += v.z; a.w += v.w;
    }
    sd[tid] = a;
    __syncthreads();
    for (int st = 128; st > 0; st >>= 1) {
        if (tid < st) {
            float4 b = sd[tid + st];
            float4 m = sd[tid];
            m.x += b.x; m.y += b.y; m.z += b.z; m.w += b.w;
            sd[tid] = m;
        }
        __syncthreads();
    }
    if (tid == 0) {
        float4 t = sd[0];
        int c0 = g * 2, c1 = g * 2 + 1;
        const float inv = 1.0f / N_NODES;
        float mu0 = t.x * inv, var0 = t.y * inv - mu0 * mu0;
        float mu1 = t.z * inv, var1 = t.w * inv - mu1 * mu1;
        float sc0 = gamma[c0] * rsqrtf(var0 + BN_EPS);
        float sc1 = gamma[c1] * rsqrtf(var1 + BN_EPS);
        scale[c0] = sc0; shift[c0] = beta[c0] - mu0 * sc0;
        scale[c1] = sc1; shift[c1] = beta[c1] - mu1 * sc1;
    }
}

// ---- weight prep: W1T = bf16(scale[k]*W1[k,m]) [M,K]; W2T/W3T plain; offsets ----
__global__ __launch_bounds__(256) void wprep_k(const float* __restrict__ W1,
                                               const float* __restrict__ W2,
                                               const float* __restrict__ W3,
                                               const float* __restrict__ scale,
                                               u16* __restrict__ W1T,
                                               u16* __restrict__ W2T,
                                               u16* __restrict__ W3T,
                                               const int* __restrict__ batch,
                                               int* __restrict__ offsets) {
    int idx = blockIdx.x * 256 + threadIdx.x;
    if (idx < 262144) {                       // W1 [512,512]
        int k = idx >> 9, m = idx & 511;
        W1T[(size_t)m * 512 + k] = f2b(scale[k] * W1[idx]);
    } else if (idx < 262144 + 131072) {       // W2 [512,256]
        int i = idx - 262144;
        int k = i >> 8, m = i & 255;
        W2T[(size_t)m * 512 + k] = f2b(W2[i]);
    } else {                                  // W3 [256,256]
        int i = idx - 393216;
        int k = i >> 8, m = i & 255;
        W3T[(size_t)m * 256 + k] = f2b(W3[i]);
    }
    if (blockIdx.x == 0 && threadIdx.x < NUM_GRAPHS) {
        int gph = threadIdx.x;
        int lo = 0, hi = N_NODES;
        while (lo < hi) {
            int mid = (lo + hi) >> 1;
            if (batch[mid] < gph) lo = mid + 1; else hi = mid;
        }
        offsets[gph] = lo;
    }
}

// ---- folded bias: b1f[m] = b1[m] + sum_k shift[k]*W1[k,m] ----
__global__ __launch_bounds__(128) void b1fold_k(const float* __restrict__ W1,
                                                const float* __restrict__ b1,
                                                const float* __restrict__ shift,
                                                float* __restrict__ b1f) {
    int m = blockIdx.x * 128 + threadIdx.x;   // 4 blocks x 128 = 512
    float acc = b1[m];
#pragma unroll 16
    for (int k = 0; k < 512; ++k) acc += shift[k] * W1[k * 512 + m];
    b1f[m] = acc;
}

// ---------------- GEMM: C[N,M] = act(A[N,K] @ BT[M,K]^T + bias) ----------------
// 128x128 block tile, BK=64, 4 waves (2x2), each wave 4x4 of 16x16x32 MFMA.
// K-group XOR swizzle: LDS stays linear (global_load_lds constraint); the
// global SOURCE column-group is permuted per row (g ^= r&7), and fragment
// reads apply the inverse. Spreads quad-group reads over all 32 banks
// (2-way aliasing = free) instead of 16-way on 4 banks.
template <int DO_GELU>
__global__ __launch_bounds__(256) void gemm_bt_k(const u16* __restrict__ A,
                                                 const u16* __restrict__ BT,
                                                 const float* __restrict__ bias,
                                                 u16* __restrict__ C,
                                                 int K, int M) {
    __shared__ __align__(16) u16 As[128 * 64];
    __shared__ __align__(16) u16 Bs[128 * 64];
    int tid = threadIdx.x;
    int lane = tid & 63;
    int row0 = blockIdx.y * 128;
    int col0 = blockIdx.x * 128;
    int wave = tid >> 6;
    int wr = (wave >> 1) * 64;
    int wc = (wave & 1) * 64;
    int l15 = lane & 15;
    int q = lane >> 4;

    floatx4 acc[4][4] = {};

    const int nkt = K >> 6;
    for (int kt = 0; kt < nkt; ++kt) {
        int k0 = kt << 6;
#pragma unroll
        for (int s = 0; s < 4; ++s) {
            int li = s * 256 + tid;
            int r = li >> 3;
            int g = li & 7;
            int gs = g ^ (r & 7);            // swizzled source group
            load_lds16(&A[(size_t)(row0 + r) * K + k0 + gs * 8], &As[li * 8]);
            load_lds16(&BT[(size_t)(col0 + r) * K + k0 + gs * 8], &Bs[li * 8]);
        }
        __syncthreads();
#pragma unroll
        for (int ks = 0; ks < 2; ++ks) {
            int gidx = ks * 4 + q;           // global k-group this quad needs
            short8 af[4], bg[4];
#pragma unroll
            for (int i = 0; i < 4; ++i) {
                int row = wr + i * 16 + l15;
                af[i] = *(const short8*)&As[row * 64 + (gidx ^ (row & 7)) * 8];
            }
#pragma unroll
            for (int j = 0; j < 4; ++j) {
                int row = wc + j * 16 + l15;
                bg[j] = *(const short8*)&Bs[row * 64 + (gidx ^ (row & 7)) * 8];
            }
#pragma unroll
            for (int i = 0; i < 4; ++i)
#pragma unroll
                for (int j = 0; j < 4; ++j)
                    acc[i][j] = __builtin_amdgcn_mfma_f32_16x16x32_bf16(af[i], bg[j], acc[i][j], 0, 0, 0);
        }
        __syncthreads();
    }
    // epilogue: C/D layout col=lane&15, row=(lane>>4)*4+reg
    int ccol = l15;
    int crow = q * 4;
#pragma unroll
    for (int j = 0; j < 4; ++j) {
        int c = col0 + wc + j * 16 + ccol;
        float b = bias[c];
#pragma unroll
        for (int i = 0; i < 4; ++i) {
            int r = row0 + wr + i * 16 + crow;
#pragma unroll
            for (int reg = 0; reg < 4; ++reg) {
                float v = acc[i][j][reg] + b;
                if (DO_GELU) v = gelu_f(v);
                C[(size_t)(r + reg) * M + c] = f2b(v);
            }
        }
    }
}

// fill entire output with head(bo) (value at padded positions)
__global__ __launch_bounds__(256) void fill_k(float* __restrict__ out,
                                              const float* __restrict__ bo,
                                              const float* __restrict__ alpha_p,
                                              const float* __restrict__ dyt_w,
                                              const float* __restrict__ dyt_b) {
    int idx = blockIdx.x * 256 + threadIdx.x;   // float4 index, 262144 total
    float alpha = alpha_p[0];
    int c0 = (idx * 4) & 7;
    float4 v;
    float* pv = &v.x;
#pragma unroll
    for (int e = 0; e < 4; ++e) {
        int c = c0 + e;
        float a = gelu_f(bo[c]);
        a = dyt_w[c] * tanhf(alpha * a) + dyt_b[c];
        pv[e] = tanhf(a);
    }
    ((float4*)out)[idx] = v;
}

// head: y = tanh(dyt_w*tanh(alpha*gelu(h3 @ Wo + bo)) + dyt_b), scattered to [pos, graph, ch]
__global__ __launch_bounds__(256) void head_k(const u16* __restrict__ h3,
                                              const float* __restrict__ Wo,
                                              const float* __restrict__ bo,
                                              const int* __restrict__ batch,
                                              const int* __restrict__ offsets,
                                              const float* __restrict__ alpha_p,
                                              const float* __restrict__ dyt_w,
                                              const float* __restrict__ dyt_b,
                                              float* __restrict__ out) {
    __shared__ float sWo[HIDDEN * OUT_CH];   // 8KB
    __shared__ int soff[NUM_GRAPHS];
    int tid = threadIdx.x;
#pragma unroll
    for (int i = 0; i < 8; ++i) sWo[i * 256 + tid] = Wo[i * 256 + tid];
    if (tid < NUM_GRAPHS) soff[tid] = offsets[tid];
    __syncthreads();
    int n = blockIdx.x * 256 + tid;
    float acc[8];
#pragma unroll
    for (int c = 0; c < 8; ++c) acc[c] = bo[c];
    const uint4* hr = (const uint4*)(h3 + (size_t)n * HIDDEN);
#pragma unroll 4
    for (int kk = 0; kk < 32; ++kk) {
        uint4 v = hr[kk];
        u32 u[4] = {v.x, v.y, v.z, v.w};
#pragma unroll
        for (int p = 0; p < 4; ++p) {
            float h0 = __uint_as_float(u[p] << 16);
            float h1 = __uint_as_float(u[p] & 0xFFFF0000u);
            const float* w0 = &sWo[(kk * 8 + p * 2) * 8];
            const float* w1 = w0 + 8;
#pragma unroll
            for (int c = 0; c < 8; ++c) acc[c] += h0 * w0[c];
#pragma unroll
            for (int c = 0; c < 8; ++c) acc[c] += h1 * w1[c];
        }
    }
    float alpha = alpha_p[0];
    int g = batch[n];
    int p = n - soff[g];
    float res[8];
#pragma unroll
    for (int c = 0; c < 8; ++c) {
        float a = gelu_f(acc[c]);
        a = dyt_w[c] * tanhf(alpha * a) + dyt_b[c];
        res[c] = tanhf(a);
    }
    float4* o = (float4*)(out + ((size_t)p * NUM_GRAPHS + g) * OUT_CH);
    o[0] = make_float4(res[0], res[1], res[2], res[3]);
    o[1] = make_float4(res[4], res[5], res[6], res[7]);
}

extern "C" void kernel_launch(void* const* d_in, const int* in_sizes, int n_in,
                              void* d_out, int out_size, void* d_ws, size_t ws_size,
                              hipStream_t stream) {
    (void)in_sizes; (void)n_in; (void)out_size; (void)ws_size;
    const float* x_res = (const float*)d_in[0];
    const int*   batch = (const int*)d_in[1];
    const float* gamma = (const float*)d_in[2];
    const float* beta  = (const float*)d_in[3];
    const float* W1    = (const float*)d_in[4];
    const float* b1    = (const float*)d_in[5];
    const float* W2    = (const float*)d_in[6];
    const float* b2    = (const float*)d_in[7];
    const float* W3    = (const float*)d_in[8];
    const float* b3    = (const float*)d_in[9];
    const float* Wo    = (const float*)d_in[10];
    const float* bo    = (const float*)d_in[11];
    const float* alpha = (const float*)d_in[12];
    const float* dyt_w = (const float*)d_in[13];
    const float* dyt_b = (const float*)d_in[14];
    float* out = (float*)d_out;

    char* ws = (char*)d_ws;
    float* scale = (float*)(ws + 0);
    float* shift = (float*)(ws + 2048);
    float* b1f   = (float*)(ws + 4096);
    int*   offs  = (int*)(ws + 8192);
    u16* W1T = (u16*)(ws + 16384);                       // 512KB
    u16* W2T = (u16*)(ws + 16384 + 524288);              // 256KB
    u16* W3T = (u16*)(ws + 16384 + 524288 + 262144);     // 128KB
    const size_t MB = 1024 * 1024;
    u16* xb = (u16*)(ws + 2 * MB);              // 64MB  [2,66)
    u16* h1 = (u16*)(ws + 66 * MB);             // 64MB  [66,130)
    u16* h2 = (u16*)(ws + 2 * MB);              // 32MB  (aliases xb; dead after GEMM1)
    u16* h3 = (u16*)(ws + 66 * MB);             // 32MB  (aliases h1; dead after GEMM2)
    float4* partials = (float4*)(ws + 66 * MB); // 8MB   (aliases h1; dead before GEMM1)

    statscast_k<<<BN_BLOCKS, 256, 0, stream>>>(x_res, xb, partials);
    bn_reduce_k<<<256, 256, 0, stream>>>(partials, gamma, beta, scale, shift);
    wprep_k<<<1792, 256, 0, stream>>>(W1, W2, W3, scale, W1T, W2T, W3T, batch, offs);
    b1fold_k<<<4, 128, 0, stream>>>(W1, b1, shift, b1f);
    gemm_bt_k<1><<<dim3(4, 512), 256, 0, stream>>>(xb, W1T, b1f, h1, 512, 512);
    gemm_bt_k<1><<<dim3(2, 512), 256, 0, stream>>>(h1, W2T, b2, h2, 512, 256);
    gemm_bt_k<0><<<dim3(2, 512), 256, 0, stream>>>(h2, W3T, b3, h3, 256, 256);
    fill_k<<<1024, 256, 0, stream>>>(out, bo, alpha, dyt_w, dyt_b);
    head_k<<<256, 256, 0, stream>>>(h3, Wo, bo, batch, offs, alpha, dyt_w, dyt_b, out);
}

// Round 5
// 403.052 us; speedup vs baseline: 1.3034x; 1.1085x over previous
//
#include <hip/hip_runtime.h>
#include <hip/hip_bf16.h>

#define N_NODES 65536
#define IN_CH 512
#define HIDDEN 256
#define OUT_CH 8
#define NUM_GRAPHS 32
#define MAX_LEN 4096
#define BN_EPS 1e-5f
#define BN_BLOCKS 2048

using short8  = __attribute__((ext_vector_type(8))) short;
using floatx4 = __attribute__((ext_vector_type(4))) float;
typedef unsigned int u32;
typedef unsigned short u16;

__device__ inline u16 f2b(float f) {
    u32 u = __float_as_uint(f);
    u += 0x7FFFu + ((u >> 16) & 1u);
    return (u16)(u >> 16);
}
// GELU tanh-form via hw exp+rcp: gelu(x) ~ x*sigmoid(1.5958*(x+0.044715x^3)).
// max abs err vs exact-erf gelu ~3e-4 << bf16 rounding already present.
__device__ inline float gelu_f(float x) {
    float z = x + 0.044715f * x * x * x;
    float e = __builtin_exp2f(-2.3022078f * z);   // exp(-1.59577*z*... ) base-2
    return x * __builtin_amdgcn_rcpf(1.0f + e);
}
__device__ inline float tanh_f(float y) {
    y = fminf(fmaxf(y, -20.0f), 20.0f);
    float t = __builtin_exp2f(2.885390082f * y);  // e^(2y)
    return (t - 1.0f) * __builtin_amdgcn_rcpf(t + 1.0f);
}
__device__ inline void load_lds16(const void* g, void* l) {
    __builtin_amdgcn_global_load_lds(
        (const __attribute__((address_space(1))) u32*)g,
        (__attribute__((address_space(3))) u32*)l, 16, 0, 0);
}

// ---- fused: per-channel sum/sumsq partials + raw bf16 cast of x ----
__global__ __launch_bounds__(256) void statscast_k(const float* __restrict__ x,
                                                   u16* __restrict__ xb,
                                                   float4* __restrict__ partials) {
    __shared__ float4 sS[128];
    __shared__ float4 sQ[128];
    int tid = threadIdx.x;
    int half = tid >> 7;
    int c = tid & 127;                  // float4 column (512ch = 128 float4)
    const float4* x4 = (const float4*)x;
    uint2* xb2 = (uint2*)xb;
    float4 s = make_float4(0.f, 0.f, 0.f, 0.f);
    float4 q = make_float4(0.f, 0.f, 0.f, 0.f);
    int row0 = blockIdx.x * 32;
#pragma unroll
    for (int r = half; r < 32; r += 2) {
        size_t off = (size_t)(row0 + r) * 128 + c;
        float4 v = x4[off];
        s.x += v.x; s.y += v.y; s.z += v.z; s.w += v.w;
        q.x += v.x * v.x; q.y += v.y * v.y; q.z += v.z * v.z; q.w += v.w * v.w;
        uint2 o;
        o.x = (u32)f2b(v.x) | ((u32)f2b(v.y) << 16);
        o.y = (u32)f2b(v.z) | ((u32)f2b(v.w) << 16);
        xb2[off] = o;
    }
    if (half == 1) { sS[c] = s; sQ[c] = q; }
    __syncthreads();
    if (half == 0) {
        float4 s2 = sS[c], q2 = sQ[c];
        s.x += s2.x; s.y += s2.y; s.z += s2.z; s.w += s2.w;
        q.x += q2.x; q.y += q2.y; q.z += q2.z; q.w += q2.w;
        partials[(size_t)blockIdx.x * 256 + c * 2]     = make_float4(s.x, q.x, s.y, q.y);
        partials[(size_t)blockIdx.x * 256 + c * 2 + 1] = make_float4(s.z, q.z, s.w, q.w);
    }
}

// ---- reduce partials -> scale/shift (block g handles channels 2g, 2g+1) ----
__global__ __launch_bounds__(256) void bn_reduce_k(const float4* __restrict__ partials,
                                                   const float* __restrict__ gamma,
                                                   const float* __restrict__ beta,
                                                   float* __restrict__ scale,
                                                   float* __restrict__ shift) {
    __shared__ float4 sd[256];
    int tid = threadIdx.x;
    int g = blockIdx.x;
    float4 a = make_float4(0.f, 0.f, 0.f, 0.f);
    for (int r = tid; r < BN_BLOCKS; r += 256) {
        float4 v = partials[(size_t)r * 256 + g];
        a.x += v.x; a.y += v.y; a.z += v.z; a.w += v.w;
    }
    sd[tid] = a;
    __syncthreads();
    for (int st = 128; st > 0; st >>= 1) {
        if (tid < st) {
            float4 b = sd[tid + st];
            float4 m = sd[tid];
            m.x += b.x; m.y += b.y; m.z += b.z; m.w += b.w;
            sd[tid] = m;
        }
        __syncthreads();
    }
    if (tid == 0) {
        float4 t = sd[0];
        int c0 = g * 2, c1 = g * 2 + 1;
        const float inv = 1.0f / N_NODES;
        float mu0 = t.x * inv, var0 = t.y * inv - mu0 * mu0;
        float mu1 = t.z * inv, var1 = t.w * inv - mu1 * mu1;
        float sc0 = gamma[c0] * rsqrtf(var0 + BN_EPS);
        float sc1 = gamma[c1] * rsqrtf(var1 + BN_EPS);
        scale[c0] = sc0; shift[c0] = beta[c0] - mu0 * sc0;
        scale[c1] = sc1; shift[c1] = beta[c1] - mu1 * sc1;
    }
}

// ---- prep: W transposes/casts + folded bias b1f + graph offsets (33 entries) ----
__global__ __launch_bounds__(256) void prep_k(const float* __restrict__ W1,
                                              const float* __restrict__ W2,
                                              const float* __restrict__ W3,
                                              const float* __restrict__ b1,
                                              const float* __restrict__ scale,
                                              const float* __restrict__ shift,
                                              u16* __restrict__ W1T,
                                              u16* __restrict__ W2T,
                                              u16* __restrict__ W3T,
                                              float* __restrict__ b1f,
                                              const int* __restrict__ batch,
                                              int* __restrict__ offsets) {
    int bid = blockIdx.x;
    int tid = threadIdx.x;
    if (bid < 1792) {
        int idx = bid * 256 + tid;
        if (idx < 262144) {                       // W1 [512,512]
            int k = idx >> 9, m = idx & 511;
            W1T[(size_t)m * 512 + k] = f2b(scale[k] * W1[idx]);
        } else if (idx < 262144 + 131072) {       // W2 [512,256]
            int i = idx - 262144;
            int k = i >> 8, m = i & 255;
            W2T[(size_t)m * 512 + k] = f2b(W2[i]);
        } else {                                  // W3 [256,256]
            int i = idx - 393216;
            int k = i >> 8, m = i & 255;
            W3T[(size_t)m * 256 + k] = f2b(W3[i]);
        }
        if (bid == 0 && tid < NUM_GRAPHS + 1) {
            int gph = tid;
            int lo = 0, hi = N_NODES;
            while (lo < hi) {
                int mid = (lo + hi) >> 1;
                if (batch[mid] < gph) lo = mid + 1; else hi = mid;
            }
            offsets[gph] = lo;
        }
    } else {                                      // b1 fold: 2 blocks x 256 = 512 m
        int m = (bid - 1792) * 256 + tid;
        float acc = b1[m];
#pragma unroll 16
        for (int k = 0; k < 512; ++k) acc += shift[k] * W1[k * 512 + m];
        b1f[m] = acc;
    }
}

// ---------------- GEMM: C[N,M] = act(A[N,K] @ BT[M,K]^T + bias) ----------------
// 128x128 block tile, BK=64, 4 waves (2x2), each wave 4x4 of 16x16x32 MFMA.
// K-group XOR swizzle on staging source + fragment reads (conflict-free).
// SWAPPED-OPERAND MFMA: mfma(bg, af) -> lane holds 4 consecutive C columns
// (m = ... + q*4 + reg), enabling 8-byte C stores and float4 bias loads.
template <int DO_GELU>
__global__ __launch_bounds__(256) void gemm_bt_k(const u16* __restrict__ A,
                                                 const u16* __restrict__ BT,
                                                 const float* __restrict__ bias,
                                                 u16* __restrict__ C,
                                                 int K, int M) {
    __shared__ __align__(16) u16 As[128 * 64];
    __shared__ __align__(16) u16 Bs[128 * 64];
    int tid = threadIdx.x;
    int lane = tid & 63;
    int row0 = blockIdx.y * 128;
    int col0 = blockIdx.x * 128;
    int wave = tid >> 6;
    int wr = (wave >> 1) * 64;
    int wc = (wave & 1) * 64;
    int l15 = lane & 15;
    int q = lane >> 4;

    floatx4 acc[4][4] = {};

    const int nkt = K >> 6;
    for (int kt = 0; kt < nkt; ++kt) {
        int k0 = kt << 6;
#pragma unroll
        for (int s = 0; s < 4; ++s) {
            int li = s * 256 + tid;
            int r = li >> 3;
            int g = li & 7;
            int gs = g ^ (r & 7);            // swizzled source group
            load_lds16(&A[(size_t)(row0 + r) * K + k0 + gs * 8], &As[li * 8]);
            load_lds16(&BT[(size_t)(col0 + r) * K + k0 + gs * 8], &Bs[li * 8]);
        }
        __syncthreads();
#pragma unroll
        for (int ks = 0; ks < 2; ++ks) {
            int gidx = ks * 4 + q;           // global k-group this quad needs
            short8 af[4], bg[4];
#pragma unroll
            for (int i = 0; i < 4; ++i) {
                int row = wr + i * 16 + l15;
                af[i] = *(const short8*)&As[row * 64 + (gidx ^ (row & 7)) * 8];
            }
#pragma unroll
            for (int j = 0; j < 4; ++j) {
                int row = wc + j * 16 + l15;
                bg[j] = *(const short8*)&Bs[row * 64 + (gidx ^ (row & 7)) * 8];
            }
#pragma unroll
            for (int i = 0; i < 4; ++i)
#pragma unroll
                for (int j = 0; j < 4; ++j)
                    acc[i][j] = __builtin_amdgcn_mfma_f32_16x16x32_bf16(bg[j], af[i], acc[i][j], 0, 0, 0);
        }
        __syncthreads();
    }
    // epilogue (swapped D layout): row n = row0+wr+i*16+l15 ; col m = col0+wc+j*16+q*4+reg
#pragma unroll
    for (int i = 0; i < 4; ++i) {
        size_t rbase = (size_t)(row0 + wr + i * 16 + l15) * M;
#pragma unroll
        for (int j = 0; j < 4; ++j) {
            int c = col0 + wc + j * 16 + q * 4;
            float4 b4 = *(const float4*)&bias[c];
            float v0 = acc[i][j][0] + b4.x;
            float v1 = acc[i][j][1] + b4.y;
            float v2 = acc[i][j][2] + b4.z;
            float v3 = acc[i][j][3] + b4.w;
            if (DO_GELU) { v0 = gelu_f(v0); v1 = gelu_f(v1); v2 = gelu_f(v2); v3 = gelu_f(v3); }
            uint2 pk;
            pk.x = (u32)f2b(v0) | ((u32)f2b(v1) << 16);
            pk.y = (u32)f2b(v2) | ((u32)f2b(v3) << 16);
            *(uint2*)&C[rbase + c] = pk;
        }
    }
}

// ---- head (destination-ordered, fill fused): for each (p,g) position ----
// valid (p < len[g]): y = tanh(dyt_w*tanh(alpha*gelu(h3[n]@Wo + bo)) + dyt_b)
// invalid: same chain with acc = bo (matches reference zero-padding).
__global__ __launch_bounds__(256) void head_k(const u16* __restrict__ h3,
                                              const float* __restrict__ Wo,
                                              const float* __restrict__ bo,
                                              const int* __restrict__ offsets,
                                              const float* __restrict__ alpha_p,
                                              const float* __restrict__ dyt_w,
                                              const float* __restrict__ dyt_b,
                                              float* __restrict__ out) {
    __shared__ float sWo[HIDDEN * OUT_CH];   // 8KB
    __shared__ int soff[NUM_GRAPHS + 1];
    int tid = threadIdx.x;
#pragma unroll
    for (int i = 0; i < 8; ++i) sWo[i * 256 + tid] = Wo[i * 256 + tid];
    if (tid < NUM_GRAPHS + 1) soff[tid] = offsets[tid];
    __syncthreads();
    int idx = blockIdx.x * 256 + tid;        // 131072 (p,g) pairs
    int g = idx & 31;
    int p = idx >> 5;
    int n = soff[g] + p;
    bool valid = n < soff[g + 1];
    float acc[8];
#pragma unroll
    for (int c = 0; c < 8; ++c) acc[c] = bo[c];
    if (valid) {
        const uint4* hr = (const uint4*)(h3 + (size_t)n * HIDDEN);
#pragma unroll 4
        for (int kk = 0; kk < 32; ++kk) {
            uint4 v = hr[kk];
            u32 u[4] = {v.x, v.y, v.z, v.w};
#pragma unroll
            for (int pp = 0; pp < 4; ++pp) {
                float h0 = __uint_as_float(u[pp] << 16);
                float h1 = __uint_as_float(u[pp] & 0xFFFF0000u);
                const float* w0 = &sWo[(kk * 8 + pp * 2) * 8];
                const float* w1 = w0 + 8;
#pragma unroll
                for (int c = 0; c < 8; ++c) acc[c] += h0 * w0[c];
#pragma unroll
                for (int c = 0; c < 8; ++c) acc[c] += h1 * w1[c];
            }
        }
    }
    float alpha = alpha_p[0];
    float res[8];
#pragma unroll
    for (int c = 0; c < 8; ++c) {
        float a = gelu_f(acc[c]);
        a = dyt_w[c] * tanh_f(alpha * a) + dyt_b[c];
        res[c] = tanh_f(a);
    }
    float4* o = (float4*)(out + (size_t)idx * OUT_CH);
    o[0] = make_float4(res[0], res[1], res[2], res[3]);
    o[1] = make_float4(res[4], res[5], res[6], res[7]);
}

extern "C" void kernel_launch(void* const* d_in, const int* in_sizes, int n_in,
                              void* d_out, int out_size, void* d_ws, size_t ws_size,
                              hipStream_t stream) {
    (void)in_sizes; (void)n_in; (void)out_size; (void)ws_size;
    const float* x_res = (const float*)d_in[0];
    const int*   batch = (const int*)d_in[1];
    const float* gamma = (const float*)d_in[2];
    const float* beta  = (const float*)d_in[3];
    const float* W1    = (const float*)d_in[4];
    const float* b1    = (const float*)d_in[5];
    const float* W2    = (const float*)d_in[6];
    const float* b2    = (const float*)d_in[7];
    const float* W3    = (const float*)d_in[8];
    const float* b3    = (const float*)d_in[9];
    const float* Wo    = (const float*)d_in[10];
    const float* bo    = (const float*)d_in[11];
    const float* alpha = (const float*)d_in[12];
    const float* dyt_w = (const float*)d_in[13];
    const float* dyt_b = (const float*)d_in[14];
    float* out = (float*)d_out;

    char* ws = (char*)d_ws;
    float* scale = (float*)(ws + 0);
    float* shift = (float*)(ws + 2048);
    float* b1f   = (float*)(ws + 4096);
    int*   offs  = (int*)(ws + 8192);
    u16* W1T = (u16*)(ws + 16384);                       // 512KB
    u16* W2T = (u16*)(ws + 16384 + 524288);              // 256KB
    u16* W3T = (u16*)(ws + 16384 + 524288 + 262144);     // 128KB
    const size_t MB = 1024 * 1024;
    u16* xb = (u16*)(ws + 2 * MB);              // 64MB  [2,66)
    u16* h1 = (u16*)(ws + 66 * MB);             // 64MB  [66,130)
    u16* h2 = (u16*)(ws + 2 * MB);              // 32MB  (aliases xb; dead after GEMM1)
    u16* h3 = (u16*)(ws + 66 * MB);             // 32MB  (aliases h1; dead after GEMM2)
    float4* partials = (float4*)(ws + 66 * MB); // 8MB   (aliases h1; dead before GEMM1)

    statscast_k<<<BN_BLOCKS, 256, 0, stream>>>(x_res, xb, partials);
    bn_reduce_k<<<256, 256, 0, stream>>>(partials, gamma, beta, scale, shift);
    prep_k<<<1794, 256, 0, stream>>>(W1, W2, W3, b1, scale, shift,
                                     W1T, W2T, W3T, b1f, batch, offs);
    gemm_bt_k<1><<<dim3(4, 512), 256, 0, stream>>>(xb, W1T, b1f, h1, 512, 512);
    gemm_bt_k<1><<<dim3(2, 512), 256, 0, stream>>>(h1, W2T, b2, h2, 512, 256);
    gemm_bt_k<0><<<dim3(2, 512), 256, 0, stream>>>(h2, W3T, b3, h3, 256, 256);
    head_k<<<512, 256, 0, stream>>>(h3, Wo, bo, offs, alpha, dyt_w, dyt_b, out);
}

// Round 6
// 375.561 us; speedup vs baseline: 1.3988x; 1.0732x over previous
//
#include <hip/hip_runtime.h>
#include <hip/hip_bf16.h>

#define N_NODES 65536
#define IN_CH 512
#define HIDDEN 256
#define OUT_CH 8
#define NUM_GRAPHS 32
#define MAX_LEN 4096
#define BN_EPS 1e-5f
#define BN_BLOCKS 2048

using short8  = __attribute__((ext_vector_type(8))) short;
using floatx4 = __attribute__((ext_vector_type(4))) float;
typedef unsigned int u32;
typedef unsigned short u16;

__device__ inline u16 f2b(float f) {
    u32 u = __float_as_uint(f);
    u += 0x7FFFu + ((u >> 16) & 1u);
    return (u16)(u >> 16);
}
// GELU tanh-form via hw exp+rcp; max abs err vs exact-erf ~3e-4.
__device__ inline float gelu_f(float x) {
    float z = x + 0.044715f * x * x * x;
    float e = __builtin_exp2f(-2.3022078f * z);
    return x * __builtin_amdgcn_rcpf(1.0f + e);
}
__device__ inline float tanh_f(float y) {
    y = fminf(fmaxf(y, -20.0f), 20.0f);
    float t = __builtin_exp2f(2.885390082f * y);
    return (t - 1.0f) * __builtin_amdgcn_rcpf(t + 1.0f);
}
__device__ inline void load_lds16(const void* g, void* l) {
    __builtin_amdgcn_global_load_lds(
        (const __attribute__((address_space(1))) u32*)g,
        (__attribute__((address_space(3))) u32*)l, 16, 0, 0);
}

// ---- fused: per-channel sum/sumsq partials + raw bf16 cast of x ----
__global__ __launch_bounds__(256) void statscast_k(const float* __restrict__ x,
                                                   u16* __restrict__ xb,
                                                   float4* __restrict__ partials) {
    __shared__ float4 sS[128];
    __shared__ float4 sQ[128];
    int tid = threadIdx.x;
    int half = tid >> 7;
    int c = tid & 127;
    const float4* x4 = (const float4*)x;
    uint2* xb2 = (uint2*)xb;
    float4 s = make_float4(0.f, 0.f, 0.f, 0.f);
    float4 q = make_float4(0.f, 0.f, 0.f, 0.f);
    int row0 = blockIdx.x * 32;
#pragma unroll
    for (int r = half; r < 32; r += 2) {
        size_t off = (size_t)(row0 + r) * 128 + c;
        float4 v = x4[off];
        s.x += v.x; s.y += v.y; s.z += v.z; s.w += v.w;
        q.x += v.x * v.x; q.y += v.y * v.y; q.z += v.z * v.z; q.w += v.w * v.w;
        uint2 o;
        o.x = (u32)f2b(v.x) | ((u32)f2b(v.y) << 16);
        o.y = (u32)f2b(v.z) | ((u32)f2b(v.w) << 16);
        xb2[off] = o;
    }
    if (half == 1) { sS[c] = s; sQ[c] = q; }
    __syncthreads();
    if (half == 0) {
        float4 s2 = sS[c], q2 = sQ[c];
        s.x += s2.x; s.y += s2.y; s.z += s2.z; s.w += s2.w;
        q.x += q2.x; q.y += q2.y; q.z += q2.z; q.w += q2.w;
        partials[(size_t)blockIdx.x * 256 + c * 2]     = make_float4(s.x, q.x, s.y, q.y);
        partials[(size_t)blockIdx.x * 256 + c * 2 + 1] = make_float4(s.z, q.z, s.w, q.w);
    }
}

// ---- reduce partials -> scale/shift ----
__global__ __launch_bounds__(256) void bn_reduce_k(const float4* __restrict__ partials,
                                                   const float* __restrict__ gamma,
                                                   const float* __restrict__ beta,
                                                   float* __restrict__ scale,
                                                   float* __restrict__ shift) {
    __shared__ float4 sd[256];
    int tid = threadIdx.x;
    int g = blockIdx.x;
    float4 a = make_float4(0.f, 0.f, 0.f, 0.f);
    for (int r = tid; r < BN_BLOCKS; r += 256) {
        float4 v = partials[(size_t)r * 256 + g];
        a.x += v.x; a.y += v.y; a.z += v.z; a.w += v.w;
    }
    sd[tid] = a;
    __syncthreads();
    for (int st = 128; st > 0; st >>= 1) {
        if (tid < st) {
            float4 b = sd[tid + st];
            float4 m = sd[tid];
            m.x += b.x; m.y += b.y; m.z += b.z; m.w += b.w;
            sd[tid] = m;
        }
        __syncthreads();
    }
    if (tid == 0) {
        float4 t = sd[0];
        int c0 = g * 2, c1 = g * 2 + 1;
        const float inv = 1.0f / N_NODES;
        float mu0 = t.x * inv, var0 = t.y * inv - mu0 * mu0;
        float mu1 = t.z * inv, var1 = t.w * inv - mu1 * mu1;
        float sc0 = gamma[c0] * rsqrtf(var0 + BN_EPS);
        float sc1 = gamma[c1] * rsqrtf(var1 + BN_EPS);
        scale[c0] = sc0; shift[c0] = beta[c0] - mu0 * sc0;
        scale[c1] = sc1; shift[c1] = beta[c1] - mu1 * sc1;
    }
}

// ---- prep: W transposes/casts + folded bias b1f + graph offsets ----
__global__ __launch_bounds__(256) void prep_k(const float* __restrict__ W1,
                                              const float* __restrict__ W2,
                                              const float* __restrict__ W3,
                                              const float* __restrict__ b1,
                                              const float* __restrict__ scale,
                                              const float* __restrict__ shift,
                                              u16* __restrict__ W1T,
                                              u16* __restrict__ W2T,
                                              u16* __restrict__ W3T,
                                              float* __restrict__ b1f,
                                              const int* __restrict__ batch,
                                              int* __restrict__ offsets) {
    int bid = blockIdx.x;
    int tid = threadIdx.x;
    if (bid < 1792) {
        int idx = bid * 256 + tid;
        if (idx < 262144) {                       // W1 [512,512]
            int k = idx >> 9, m = idx & 511;
            W1T[(size_t)m * 512 + k] = f2b(scale[k] * W1[idx]);
        } else if (idx < 262144 + 131072) {       // W2 [512,256]
            int i = idx - 262144;
            int k = i >> 8, m = i & 255;
            W2T[(size_t)m * 512 + k] = f2b(W2[i]);
        } else {                                  // W3 [256,256]
            int i = idx - 393216;
            int k = i >> 8, m = i & 255;
            W3T[(size_t)m * 256 + k] = f2b(W3[i]);
        }
        if (bid == 0 && tid < NUM_GRAPHS + 1) {
            int gph = tid;
            int lo = 0, hi = N_NODES;
            while (lo < hi) {
                int mid = (lo + hi) >> 1;
                if (batch[mid] < gph) lo = mid + 1; else hi = mid;
            }
            offsets[gph] = lo;
        }
    } else {
        int m = (bid - 1792) * 256 + tid;
        float acc = b1[m];
#pragma unroll 16
        for (int k = 0; k < 512; ++k) acc += shift[k] * W1[k * 512 + m];
        b1f[m] = acc;
    }
}

// ---------------- GEMM: C[N,M] = act(A[N,K] @ BT[M,K]^T + bias) ----------------
// 256x128 block tile, 512 threads (8 waves, 4x2), BK=64, 4x4 MFMA per wave.
// XCD-aware remap: bid&7 = XCD; each XCD owns 32 contiguous row-tiles and
// sweeps cols within them, so col-blocks sharing an A-tile hit one L2.
// K-group XOR swizzle (conflict-free) + swapped-operand MFMA (8B C-stores).
template <int DO_GELU, int NXB>
__global__ __launch_bounds__(512) void gemm_bt_k(const u16* __restrict__ A,
                                                 const u16* __restrict__ BT,
                                                 const float* __restrict__ bias,
                                                 u16* __restrict__ C,
                                                 int K, int M) {
    __shared__ __align__(16) u16 As[256 * 64];   // 32KB
    __shared__ __align__(16) u16 Bs[128 * 64];   // 16KB
    int tid = threadIdx.x;
    int lane = tid & 63;
    int bid = blockIdx.x;
    int xcd = bid & 7;
    int slot = bid >> 3;
    int rloc = slot / NXB;
    int colb = slot - rloc * NXB;
    int row0 = (xcd * 32 + rloc) * 256;
    int col0 = colb * 128;
    int wave = tid >> 6;
    int wr = (wave >> 1) * 64;     // 0..192
    int wc = (wave & 1) * 64;      // 0/64
    int l15 = lane & 15;
    int q = lane >> 4;

    floatx4 acc[4][4] = {};

    const int nkt = K >> 6;
    for (int kt = 0; kt < nkt; ++kt) {
        int k0 = kt << 6;
#pragma unroll
        for (int s = 0; s < 4; ++s) {            // A: 256x64 = 2048 chunks
            int li = s * 512 + tid;
            int r = li >> 3;
            int g = li & 7;
            int gs = g ^ (r & 7);
            load_lds16(&A[(size_t)(row0 + r) * K + k0 + gs * 8], &As[li * 8]);
        }
#pragma unroll
        for (int s = 0; s < 2; ++s) {            // B: 128x64 = 1024 chunks
            int li = s * 512 + tid;
            int r = li >> 3;
            int g = li & 7;
            int gs = g ^ (r & 7);
            load_lds16(&BT[(size_t)(col0 + r) * K + k0 + gs * 8], &Bs[li * 8]);
        }
        __syncthreads();
#pragma unroll
        for (int ks = 0; ks < 2; ++ks) {
            int gidx = ks * 4 + q;
            short8 af[4], bg[4];
#pragma unroll
            for (int i = 0; i < 4; ++i) {
                int row = wr + i * 16 + l15;
                af[i] = *(const short8*)&As[row * 64 + (gidx ^ (row & 7)) * 8];
            }
#pragma unroll
            for (int j = 0; j < 4; ++j) {
                int row = wc + j * 16 + l15;
                bg[j] = *(const short8*)&Bs[row * 64 + (gidx ^ (row & 7)) * 8];
            }
#pragma unroll
            for (int i = 0; i < 4; ++i)
#pragma unroll
                for (int j = 0; j < 4; ++j)
                    acc[i][j] = __builtin_amdgcn_mfma_f32_16x16x32_bf16(bg[j], af[i], acc[i][j], 0, 0, 0);
        }
        __syncthreads();
    }
    // epilogue (swapped D): row = row0+wr+i*16+l15 ; col = col0+wc+j*16+q*4+reg
#pragma unroll
    for (int i = 0; i < 4; ++i) {
        size_t rbase = (size_t)(row0 + wr + i * 16 + l15) * M;
#pragma unroll
        for (int j = 0; j < 4; ++j) {
            int c = col0 + wc + j * 16 + q * 4;
            float4 b4 = *(const float4*)&bias[c];
            float v0 = acc[i][j][0] + b4.x;
            float v1 = acc[i][j][1] + b4.y;
            float v2 = acc[i][j][2] + b4.z;
            float v3 = acc[i][j][3] + b4.w;
            if (DO_GELU) { v0 = gelu_f(v0); v1 = gelu_f(v1); v2 = gelu_f(v2); v3 = gelu_f(v3); }
            uint2 pk;
            pk.x = (u32)f2b(v0) | ((u32)f2b(v1) << 16);
            pk.y = (u32)f2b(v2) | ((u32)f2b(v3) << 16);
            *(uint2*)&C[rbase + c] = pk;
        }
    }
}

// ---- head (destination-ordered, fill fused) ----
__global__ __launch_bounds__(256) void head_k(const u16* __restrict__ h3,
                                              const float* __restrict__ Wo,
                                              const float* __restrict__ bo,
                                              const int* __restrict__ offsets,
                                              const float* __restrict__ alpha_p,
                                              const float* __restrict__ dyt_w,
                                              const float* __restrict__ dyt_b,
                                              float* __restrict__ out) {
    __shared__ float sWo[HIDDEN * OUT_CH];
    __shared__ int soff[NUM_GRAPHS + 1];
    int tid = threadIdx.x;
#pragma unroll
    for (int i = 0; i < 8; ++i) sWo[i * 256 + tid] = Wo[i * 256 + tid];
    if (tid < NUM_GRAPHS + 1) soff[tid] = offsets[tid];
    __syncthreads();
    int idx = blockIdx.x * 256 + tid;
    int g = idx & 31;
    int p = idx >> 5;
    int n = soff[g] + p;
    bool valid = n < soff[g + 1];
    float acc[8];
#pragma unroll
    for (int c = 0; c < 8; ++c) acc[c] = bo[c];
    if (valid) {
        const uint4* hr = (const uint4*)(h3 + (size_t)n * HIDDEN);
#pragma unroll 4
        for (int kk = 0; kk < 32; ++kk) {
            uint4 v = hr[kk];
            u32 u[4] = {v.x, v.y, v.z, v.w};
#pragma unroll
            for (int pp = 0; pp < 4; ++pp) {
                float h0 = __uint_as_float(u[pp] << 16);
                float h1 = __uint_as_float(u[pp] & 0xFFFF0000u);
                const float* w0 = &sWo[(kk * 8 + pp * 2) * 8];
                const float* w1 = w0 + 8;
#pragma unroll
                for (int c = 0; c < 8; ++c) acc[c] += h0 * w0[c];
#pragma unroll
                for (int c = 0; c < 8; ++c) acc[c] += h1 * w1[c];
            }
        }
    }
    float alpha = alpha_p[0];
    float res[8];
#pragma unroll
    for (int c = 0; c < 8; ++c) {
        float a = gelu_f(acc[c]);
        a = dyt_w[c] * tanh_f(alpha * a) + dyt_b[c];
        res[c] = tanh_f(a);
    }
    float4* o = (float4*)(out + (size_t)idx * OUT_CH);
    o[0] = make_float4(res[0], res[1], res[2], res[3]);
    o[1] = make_float4(res[4], res[5], res[6], res[7]);
}

extern "C" void kernel_launch(void* const* d_in, const int* in_sizes, int n_in,
                              void* d_out, int out_size, void* d_ws, size_t ws_size,
                              hipStream_t stream) {
    (void)in_sizes; (void)n_in; (void)out_size; (void)ws_size;
    const float* x_res = (const float*)d_in[0];
    const int*   batch = (const int*)d_in[1];
    const float* gamma = (const float*)d_in[2];
    const float* beta  = (const float*)d_in[3];
    const float* W1    = (const float*)d_in[4];
    const float* b1    = (const float*)d_in[5];
    const float* W2    = (const float*)d_in[6];
    const float* b2    = (const float*)d_in[7];
    const float* W3    = (const float*)d_in[8];
    const float* b3    = (const float*)d_in[9];
    const float* Wo    = (const float*)d_in[10];
    const float* bo    = (const float*)d_in[11];
    const float* alpha = (const float*)d_in[12];
    const float* dyt_w = (const float*)d_in[13];
    const float* dyt_b = (const float*)d_in[14];
    float* out = (float*)d_out;

    char* ws = (char*)d_ws;
    float* scale = (float*)(ws + 0);
    float* shift = (float*)(ws + 2048);
    float* b1f   = (float*)(ws + 4096);
    int*   offs  = (int*)(ws + 8192);
    u16* W1T = (u16*)(ws + 16384);                       // 512KB
    u16* W2T = (u16*)(ws + 16384 + 524288);              // 256KB
    u16* W3T = (u16*)(ws + 16384 + 524288 + 262144);     // 128KB
    const size_t MB = 1024 * 1024;
    u16* xb = (u16*)(ws + 2 * MB);              // 64MB  [2,66)
    u16* h1 = (u16*)(ws + 66 * MB);             // 64MB  [66,130)
    u16* h2 = (u16*)(ws + 2 * MB);              // 32MB  (aliases xb)
    u16* h3 = (u16*)(ws + 66 * MB);             // 32MB  (aliases h1)
    float4* partials = (float4*)(ws + 66 * MB); // 8MB   (aliases h1; dead before GEMM1)

    statscast_k<<<BN_BLOCKS, 256, 0, stream>>>(x_res, xb, partials);
    bn_reduce_k<<<256, 256, 0, stream>>>(partials, gamma, beta, scale, shift);
    prep_k<<<1794, 256, 0, stream>>>(W1, W2, W3, b1, scale, shift,
                                     W1T, W2T, W3T, b1f, batch, offs);
    gemm_bt_k<1, 4><<<1024, 512, 0, stream>>>(xb, W1T, b1f, h1, 512, 512);
    gemm_bt_k<1, 2><<<512, 512, 0, stream>>>(h1, W2T, b2, h2, 512, 256);
    gemm_bt_k<0, 2><<<512, 512, 0, stream>>>(h2, W3T, b3, h3, 256, 256);
    head_k<<<512, 256, 0, stream>>>(h3, Wo, bo, offs, alpha, dyt_w, dyt_b, out);
}